// Round 5
// baseline (551.295 us; speedup 1.0000x reference)
//
#include <hip/hip_runtime.h>
#include <hip/hip_bf16.h>
#include <math.h>

// SimpleEdgePredictor on MI355X — R5.
//   proj: MFMA bf16 GEMM (node projections, W-half staged in LDS once/block)
//   edge: GEMM1 with sigma-permuted channel tiling so GEMM2's B-fragments
//         come straight from GEMM1's accumulators (no LDS transpose buffer).
//   sigma(nt=2a+b, row=4q+j) = 32a+8q+4b+j  ->  lane(q,c15) acc[2a+b][j]
//   holds channel 32a+8q+4b+j of edge c15 == B-frag slot i=4b+j of chunk a.
// LDS: edge 34816B -> 4 blocks/CU (was 67584 -> 2).
// Swizzle swz(R) = ((R&3)<<2) ^ (((R>>3)&1)<<4): per-phase 8 quads x 2 lanes
// (conflict-free b128).

#define HID   128
#define HID2  256
#define NG    64
#define NET   8
#define NB    256
#define NMOL  64
#define MAXF  16

// P row layout (rows of 256 f32):
//   [0,16384) mol | [16384,20480) fa | [20480,24576) bff(+b1) | [24576,28672) bmf(+w320)
#define PMOL   16384
#define R_FA   16384
#define R_BFF  20480
#define R_BMF  24576

#define E_FF     65536
#define TILES_FF 4096
#define NTILES   20480

#define EDGE_LDS_WORDS (8192 + 512)            // W1T + ln params
#define EDGE_LDS_BYTES (EDGE_LDS_WORDS*4)      // 34816
#define PROJ_LDS_BYTES (256*64*4)              // 65536

typedef float f32x4 __attribute__((ext_vector_type(4)));
typedef short bf16x8 __attribute__((ext_vector_type(8)));
union U4 { uint4 u; bf16x8 b; };

__device__ __forceinline__ unsigned pk_bf16(float lo, float hi) {
    __hip_bfloat162 h = __float22bfloat162_rn(float2{lo, hi});
    union { __hip_bfloat162 h; unsigned u; } c; c.h = h;
    return c.u;
}

// ---------------- proj: P[node] = h[node] @ Whalf (MFMA) ----------------
// blocks: [0,256) mol-a | [256,320) frag-a | [320,384) frag-b (dual store)
__global__ __launch_bounds__(256,2) void proj_kernel(
    const float* __restrict__ h_mol, const float* __restrict__ h_frag,
    const float* __restrict__ W1, const float* __restrict__ b1,
    float* __restrict__ P)
{
    extern __shared__ unsigned WT[];           // [256 ch][64 words], swizzled
    const int tid = threadIdx.x, lane = tid & 63, wid = tid >> 6;
    const int c15 = lane & 15, q = lane >> 4;
    const int blk = blockIdx.x;

    int wrow0, mode, nloc0; const float* src; int dr0;
    if (blk < 256)      { mode=0; wrow0=0;   src=h_mol;  nloc0 = blk*64;       dr0 = nloc0; }
    else if (blk < 320) { mode=0; wrow0=0;   src=h_frag; nloc0 = (blk-256)*64; dr0 = R_FA + nloc0; }
    else                { mode=1; wrow0=HID; src=h_frag; nloc0 = (blk-320)*64; dr0 = R_BFF + nloc0; }

    // stage Whalf transposed -> bf16 [ch][k], swizzled; thread = column ch=tid
    {
        const float* colp = W1 + (size_t)wrow0*HID2 + tid;
        const unsigned swzS = ((unsigned)(tid&3)<<2) ^ ((unsigned)((tid>>3)&1)<<4);
        #pragma unroll 8
        for (int k2 = 0; k2 < 64; ++k2) {
            const float a0 = colp[(2*k2  )*HID2];
            const float a1 = colp[(2*k2+1)*HID2];
            WT[(unsigned)tid*64 + (((unsigned)k2) ^ swzS)] = pk_bf16(a0, a1);
        }
    }
    __syncthreads();

    const int nloc = nloc0 + wid*16 + c15;     // this lane's node (column)
    const float* hp = src + (size_t)nloc*HID;

    // B-fragments: h[node][32kc+8q+i], i=0..7
    U4 bB[4];
    #pragma unroll
    for (int kc = 0; kc < 4; ++kc) {
        const float4 lo = *(const float4*)(hp + 32*kc + 8*q);
        const float4 hi = *(const float4*)(hp + 32*kc + 8*q + 4);
        bB[kc].u = make_uint4(pk_bf16(lo.x,lo.y), pk_bf16(lo.z,lo.w),
                              pk_bf16(hi.x,hi.y), pk_bf16(hi.z,hi.w));
    }

    const unsigned szA = ((unsigned)(c15&3)<<2) ^ ((unsigned)((c15>>3)&1)<<4);
    f32x4 acc[16];
    #pragma unroll
    for (int nt = 0; nt < 16; ++nt) {
        f32x4 c;
        if (mode == 1) {
            const float4 bi = *(const float4*)(b1 + 16*nt + 4*q);
            c.x = bi.x; c.y = bi.y; c.z = bi.z; c.w = bi.w;
        } else { c.x = 0.f; c.y = 0.f; c.z = 0.f; c.w = 0.f; }
        const unsigned rowbase = (unsigned)(16*nt + c15)*64;
        #pragma unroll
        for (int kc = 0; kc < 4; ++kc) {
            U4 a;
            a.u = *(const uint4*)&WT[rowbase + (((unsigned)(16*kc + 4*q)) ^ szA)];
            c = __builtin_amdgcn_mfma_f32_16x16x32_bf16(a.b, bB[kc].b, c, 0, 0, 0);
        }
        acc[nt] = c;
    }

    // store: lane(q,c15) reg j = channel 16nt+4q+j of node
    const int drow = dr0 + wid*16 + c15;
    float* d1 = P + (size_t)drow*HID2 + 4*q;
    if (mode == 0) {
        #pragma unroll
        for (int nt = 0; nt < 16; ++nt)
            *(float4*)(d1 + 16*nt) = make_float4(acc[nt].x, acc[nt].y, acc[nt].z, acc[nt].w);
    } else {
        float* d2 = d1 + (size_t)4096*HID2;    // bmf twin
        #pragma unroll
        for (int nt = 0; nt < 16; ++nt) {
            const float4 w3 = *(const float4*)(W1 + (size_t)320*HID2 + 16*nt + 4*q);
            const float4 v = make_float4(acc[nt].x, acc[nt].y, acc[nt].z, acc[nt].w);
            *(float4*)(d1 + 16*nt) = v;
            *(float4*)(d2 + 16*nt) = make_float4(v.x+w3.x, v.y+w3.y, v.z+w3.z, v.w+w3.w);
        }
    }
}

// ---------------- per-edge MFMA kernel ----------------
__global__ __launch_bounds__(256,4) void edge_kernel(
    const float* __restrict__ pos_mol, const float* __restrict__ pos_frag,
    const float* __restrict__ W1, const float* __restrict__ ln_g,
    const float* __restrict__ ln_b, const float* __restrict__ W2,
    const float* __restrict__ b2, const float* __restrict__ P,
    float* __restrict__ out)
{
    extern __shared__ unsigned sm[];
    unsigned* W1T = sm;                  // [256 ch][32 words], swizzled
    float*    pp  = (float*)(sm + 8192); // [256 ch][2] = (ln_g, ln_b)
    const int tid = threadIdx.x, lane = tid & 63, wid = tid >> 6;
    const int c15 = lane & 15, q = lane >> 4;

    // ---- stage W1 rows 256..319 transposed (bf16 [ch][k=64]), swizzled ----
    {
        const float* colp = W1 + (size_t)256*HID2 + tid;
        const unsigned swzS = ((unsigned)(tid&3)<<2) ^ ((unsigned)((tid>>3)&1)<<4);
        #pragma unroll 4
        for (int k3 = 0; k3 < 16; ++k3) {
            const float a0 = colp[(4*k3+0)*HID2];
            const float a1 = colp[(4*k3+1)*HID2];
            const float a2 = colp[(4*k3+2)*HID2];
            const float a3 = colp[(4*k3+3)*HID2];
            const unsigned w = (unsigned)tid*32 + (((unsigned)(2*k3)) ^ swzS);
            *(uint2*)&W1T[w] = make_uint2(pk_bf16(a0, a1), pk_bf16(a2, a3));
        }
        pp[2*tid]   = ln_g[tid];
        pp[2*tid+1] = ln_b[tid];
    }

    // ---- W2^T A-fragments, register-resident (rows o>=8 zero) ----
    unsigned a2f[8][4];
    {
        const int o = c15;
        #pragma unroll
        for (int ks = 0; ks < 8; ++ks)
            #pragma unroll
            for (int j = 0; j < 4; ++j) {
                float lo = 0.f, hi = 0.f;
                if (o < 8) {
                    lo = W2[(size_t)(32*ks + 8*q + 2*j    )*NET + o];
                    hi = W2[(size_t)(32*ks + 8*q + 2*j + 1)*NET + o];
                }
                a2f[ks][j] = pk_bf16(lo, hi);
            }
    }
    float4 b2v = make_float4(0.f,0.f,0.f,0.f);
    if (q < 2) b2v = ((const float4*)b2)[q];

    // ---- gaussian slot tables (lane-const): k = 32*(s>>3) + 8q + (s&7) ----
    const float delta = 10.0f/63.0f;
    const float coeff = -0.5f/(delta*delta);
    const float cl2e  = coeff * 1.44269504088896340736f;
    float c1t[16], c2t[16];
    #pragma unroll
    for (int s = 0; s < 16; ++s) {
        const int k = 32*(s>>3) + 8*q + (s&7);
        const float off = delta * (float)k;
        c1t[s] = off;
        c2t[s] = cl2e*off*off;
    }

    // A-read swizzle & lane-const address parts (sigma rows):
    //   R = 32a + 4b + 8*(c15>>2) + (c15&3); swz(R) depends only on c15.
    const unsigned szA = ((unsigned)(c15&3)<<2) ^ ((unsigned)((c15>>2)&1)<<4);
    const unsigned laneRow = (unsigned)(c15>>2)*256 + (unsigned)(c15&3)*32;
    const unsigned kt0 = ((unsigned)(4*q))      ^ szA;   // kc=0
    const unsigned kt1 = ((unsigned)(16 + 4*q)) ^ szA;   // kc=1
    __syncthreads();

    #pragma unroll 1
    for (int it = 0; it < 5; ++it) {
        const int tile = blockIdx.x*20 + it*4 + wid;
        const bool isff = (tile < TILES_FF);
        int arow, browbase;
        const float* pa; const float* Pa; const float* Pb;
        size_t obase;
        if (isff) {
            const int bg = tile >> 4, i = tile & 15;
            arow = bg*MAXF + i; browbase = bg*MAXF;
            pa = pos_frag + (size_t)arow*3;
            Pa = P + (size_t)(R_FA + arow)*HID2;
            Pb = P + (size_t)(R_BFF + browbase)*HID2;
            obase = (size_t)(tile << 4) * NET;
        } else {
            const int tt = tile - TILES_FF, bg = tt >> 6, m = tt & 63;
            arow = bg*NMOL + m; browbase = bg*MAXF;
            pa = pos_mol + (size_t)arow*3;
            Pa = P + (size_t)arow*HID2;
            Pb = P + (size_t)(R_BMF + browbase)*HID2;
            obase = (size_t)(E_FF + (tt << 4)) * NET;
        }

        // distance for this lane's edge (col = c15)
        const float* pb = pos_frag + (size_t)(browbase + c15)*3;
        const float dx = pa[0]-pb[0], dy = pa[1]-pb[1], dz = pa[2]-pb[2];
        const float d  = sqrtf(fmaf(dx,dx, fmaf(dy,dy, fmaf(dz,dz, 1e-12f))));
        const float Ad = cl2e*d*d;
        const float Bd = -2.f*cl2e*d;

        // g B-fragments in-register
        U4 gB0, gB1;
        {
            unsigned g0[4], g1[4];
            #pragma unroll
            for (int j = 0; j < 4; ++j) {
                const float e0 = exp2f(fmaf(Bd, c1t[2*j  ], c2t[2*j  ]) + Ad);
                const float e1 = exp2f(fmaf(Bd, c1t[2*j+1], c2t[2*j+1]) + Ad);
                g0[j] = pk_bf16(e0, e1);
                const float e2 = exp2f(fmaf(Bd, c1t[8+2*j  ], c2t[8+2*j  ]) + Ad);
                const float e3 = exp2f(fmaf(Bd, c1t[8+2*j+1], c2t[8+2*j+1]) + Ad);
                g1[j] = pk_bf16(e2, e3);
            }
            gB0.u = make_uint4(g0[0], g0[1], g0[2], g0[3]);
            gB1.u = make_uint4(g1[0], g1[1], g1[2], g1[3]);
        }

        // GEMM1 with sigma rows: acc[2a+b] holds channels 32a+8q+4b+(0..3)
        f32x4 acc[16];
        const float* PaQ = Pa + 8*q;
        const float* PbQ = Pb + (size_t)c15*HID2 + 8*q;
        #pragma unroll
        for (int nt = 0; nt < 16; ++nt) {
            const int ofs = 32*(nt>>1) + 4*(nt&1);             // + 8q in bases
            const unsigned wbase = laneRow + (unsigned)(1024*(nt>>1) + 128*(nt&1));
            U4 a1a, a1b;
            a1a.u = *(const uint4*)&W1T[wbase + kt0];
            a1b.u = *(const uint4*)&W1T[wbase + kt1];
            const float4 pa4 = *(const float4*)(PaQ + ofs);
            const float4 pb4 = *(const float4*)(PbQ + ofs);
            f32x4 c;
            c.x = pa4.x + pb4.x; c.y = pa4.y + pb4.y;
            c.z = pa4.z + pb4.z; c.w = pa4.w + pb4.w;
            c = __builtin_amdgcn_mfma_f32_16x16x32_bf16(a1a.b, gB0.b, c, 0, 0, 0);
            c = __builtin_amdgcn_mfma_f32_16x16x32_bf16(a1b.b, gB1.b, c, 0, 0, 0);
            acc[nt] = c;
        }

        // LayerNorm stats (lane holds 64 channels; reduce over q-lanes)
        float s1 = 0.f, s2 = 0.f;
        #pragma unroll
        for (int nt = 0; nt < 16; ++nt) {
            const f32x4 c = acc[nt];
            s1 += (c.x + c.y) + (c.z + c.w);
            s2  = fmaf(c.x,c.x, fmaf(c.y,c.y, fmaf(c.z,c.z, fmaf(c.w,c.w, s2))));
        }
        s1 += __shfl_xor(s1, 16, 64); s1 += __shfl_xor(s1, 32, 64);
        s2 += __shfl_xor(s2, 16, 64); s2 += __shfl_xor(s2, 32, 64);
        const float mu  = s1 * (1.f/HID2);
        const float var = fmaf(-mu, mu, s2 * (1.f/HID2));
        const float rs  = rsqrtf(var + 1e-5f);
        const float c0  = -mu * rs;

        // LN + ReLU + pack: acc pair (2a, 2a+1) IS GEMM2's B-frag chunk a
        f32x4 o2 = {0.f, 0.f, 0.f, 0.f};
        #pragma unroll
        for (int a = 0; a < 8; ++a) {
            unsigned hh[4];
            #pragma unroll
            for (int b = 0; b < 2; ++b) {
                const int nt = 2*a + b;
                const float* pq = pp + (32*a + 4*b + 8*q)*2;
                const float4 g01 = *(const float4*)pq;
                const float4 g23 = *(const float4*)(pq + 4);
                const f32x4 c = acc[nt];
                const float h0 = fmaxf(fmaf(fmaf(c.x, rs, c0), g01.x, g01.y), 0.f);
                const float h1 = fmaxf(fmaf(fmaf(c.y, rs, c0), g01.z, g01.w), 0.f);
                const float h2 = fmaxf(fmaf(fmaf(c.z, rs, c0), g23.x, g23.y), 0.f);
                const float h3 = fmaxf(fmaf(fmaf(c.w, rs, c0), g23.z, g23.w), 0.f);
                hh[2*b]   = pk_bf16(h0, h1);
                hh[2*b+1] = pk_bf16(h2, h3);
            }
            U4 a2u, b2u;
            a2u.u = make_uint4(a2f[a][0], a2f[a][1], a2f[a][2], a2f[a][3]);
            b2u.u = make_uint4(hh[0], hh[1], hh[2], hh[3]);
            o2 = __builtin_amdgcn_mfma_f32_16x16x32_bf16(a2u.b, b2u.b, o2, 0, 0, 0);
        }

        // store: D rows 0..7 = outputs; lane (q<2, c15): edge c15, o = 4q+j
        if (lane < 32) {
            const float4 r = make_float4(o2.x + b2v.x, o2.y + b2v.y,
                                         o2.z + b2v.z, o2.w + b2v.w);
            *(float4*)(out + obase + (size_t)c15*NET + 4*q) = r;
        }
    }
}

extern "C" void kernel_launch(void* const* d_in, const int* in_sizes, int n_in,
                              void* d_out, int out_size, void* d_ws, size_t ws_size,
                              hipStream_t stream)
{
    const float* h_mol    = (const float*)d_in[0];
    const float* pos_mol  = (const float*)d_in[1];
    const float* h_frag   = (const float*)d_in[2];
    const float* pos_frag = (const float*)d_in[3];
    // d_in[4], d_in[5]: batch indices — contiguous per-graph layout, unused
    const float* W1   = (const float*)d_in[6];
    const float* b1   = (const float*)d_in[7];
    const float* ln_g = (const float*)d_in[8];
    const float* ln_b = (const float*)d_in[9];
    const float* W2   = (const float*)d_in[10];
    const float* b2   = (const float*)d_in[11];

    float* P    = (float*)d_ws;       // 28672 * 256 f32 = 29.36 MB
    float* outp = (float*)d_out;

    hipFuncSetAttribute((const void*)proj_kernel,
                        hipFuncAttributeMaxDynamicSharedMemorySize, PROJ_LDS_BYTES);
    proj_kernel<<<384, 256, PROJ_LDS_BYTES, stream>>>(h_mol, h_frag, W1, b1, P);

    edge_kernel<<<1024, 256, EDGE_LDS_BYTES, stream>>>(
        pos_mol, pos_frag, W1, ln_g, ln_b, W2, b2, P, outp);
}

// Round 7
// 481.850 us; speedup vs baseline: 1.1441x; 1.1441x over previous
//
#include <hip/hip_runtime.h>
#include <hip/hip_bf16.h>
#include <math.h>

// SimpleEdgePredictor on MI355X — R6 = R5 sigma-structure + register diet.
// R5 failure: launch_bounds(256,4) capped VGPR at 128 vs ~160 demand ->
// acc spilled to scratch (FETCH 866MB, WRITE 334MB). R6 removes 64 regs of
// demand: W2T frags -> 4KB LDS (slot=tid), gaussian tables -> inline compute.
// LDS 38912B -> 4 blocks/CU, VGPR ~105 <= 128 -> 50% occupancy, no spills.

#define HID   128
#define HID2  256
#define NG    64
#define NET   8
#define NB    256
#define NMOL  64
#define MAXF  16

// P row layout (rows of 256 f32):
//   [0,16384) mol | [16384,20480) fa | [20480,24576) bff(+b1) | [24576,28672) bmf(+w320)
#define PMOL   16384
#define R_FA   16384
#define R_BFF  20480
#define R_BMF  24576

#define E_FF     65536
#define TILES_FF 4096
#define NTILES   20480

#define EDGE_LDS_WORDS (8192 + 512 + 1024)     // W1T + ln params + W2T frags
#define EDGE_LDS_BYTES (EDGE_LDS_WORDS*4)      // 38912 -> 4 blocks/CU
#define PROJ_LDS_BYTES (256*64*4)              // 65536

typedef float f32x4 __attribute__((ext_vector_type(4)));
typedef short bf16x8 __attribute__((ext_vector_type(8)));
union U4 { uint4 u; bf16x8 b; };

__device__ __forceinline__ unsigned pk_bf16(float lo, float hi) {
    __hip_bfloat162 h = __float22bfloat162_rn(float2{lo, hi});
    union { __hip_bfloat162 h; unsigned u; } c; c.h = h;
    return c.u;
}

// ---------------- proj: P[node] = h[node] @ Whalf (MFMA) ----------------
// blocks: [0,256) mol-a | [256,320) frag-a | [320,384) frag-b (dual store)
__global__ __launch_bounds__(256,2) void proj_kernel(
    const float* __restrict__ h_mol, const float* __restrict__ h_frag,
    const float* __restrict__ W1, const float* __restrict__ b1,
    float* __restrict__ P)
{
    extern __shared__ unsigned WT[];           // [256 ch][64 words], swizzled
    const int tid = threadIdx.x, lane = tid & 63, wid = tid >> 6;
    const int c15 = lane & 15, q = lane >> 4;
    const int blk = blockIdx.x;

    int wrow0, mode, nloc0; const float* src; int dr0;
    if (blk < 256)      { mode=0; wrow0=0;   src=h_mol;  nloc0 = blk*64;       dr0 = nloc0; }
    else if (blk < 320) { mode=0; wrow0=0;   src=h_frag; nloc0 = (blk-256)*64; dr0 = R_FA + nloc0; }
    else                { mode=1; wrow0=HID; src=h_frag; nloc0 = (blk-320)*64; dr0 = R_BFF + nloc0; }

    // stage Whalf transposed -> bf16 [ch][k], swizzled; thread = column ch=tid
    {
        const float* colp = W1 + (size_t)wrow0*HID2 + tid;
        const unsigned swzS = ((unsigned)(tid&3)<<2) ^ ((unsigned)((tid>>3)&1)<<4);
        #pragma unroll 8
        for (int k2 = 0; k2 < 64; ++k2) {
            const float a0 = colp[(2*k2  )*HID2];
            const float a1 = colp[(2*k2+1)*HID2];
            WT[(unsigned)tid*64 + (((unsigned)k2) ^ swzS)] = pk_bf16(a0, a1);
        }
    }
    __syncthreads();

    const int nloc = nloc0 + wid*16 + c15;     // this lane's node (column)
    const float* hp = src + (size_t)nloc*HID;

    // B-fragments: h[node][32kc+8q+i], i=0..7
    U4 bB[4];
    #pragma unroll
    for (int kc = 0; kc < 4; ++kc) {
        const float4 lo = *(const float4*)(hp + 32*kc + 8*q);
        const float4 hi = *(const float4*)(hp + 32*kc + 8*q + 4);
        bB[kc].u = make_uint4(pk_bf16(lo.x,lo.y), pk_bf16(lo.z,lo.w),
                              pk_bf16(hi.x,hi.y), pk_bf16(hi.z,hi.w));
    }

    const unsigned szA = ((unsigned)(c15&3)<<2) ^ ((unsigned)((c15>>3)&1)<<4);
    f32x4 acc[16];
    #pragma unroll
    for (int nt = 0; nt < 16; ++nt) {
        f32x4 c;
        if (mode == 1) {
            const float4 bi = *(const float4*)(b1 + 16*nt + 4*q);
            c.x = bi.x; c.y = bi.y; c.z = bi.z; c.w = bi.w;
        } else { c.x = 0.f; c.y = 0.f; c.z = 0.f; c.w = 0.f; }
        const unsigned rowbase = (unsigned)(16*nt + c15)*64;
        #pragma unroll
        for (int kc = 0; kc < 4; ++kc) {
            U4 a;
            a.u = *(const uint4*)&WT[rowbase + (((unsigned)(16*kc + 4*q)) ^ szA)];
            c = __builtin_amdgcn_mfma_f32_16x16x32_bf16(a.b, bB[kc].b, c, 0, 0, 0);
        }
        acc[nt] = c;
    }

    // store: lane(q,c15) reg j = channel 16nt+4q+j of node
    const int drow = dr0 + wid*16 + c15;
    float* d1 = P + (size_t)drow*HID2 + 4*q;
    if (mode == 0) {
        #pragma unroll
        for (int nt = 0; nt < 16; ++nt)
            *(float4*)(d1 + 16*nt) = make_float4(acc[nt].x, acc[nt].y, acc[nt].z, acc[nt].w);
    } else {
        float* d2 = d1 + (size_t)4096*HID2;    // bmf twin
        #pragma unroll
        for (int nt = 0; nt < 16; ++nt) {
            const float4 w3 = *(const float4*)(W1 + (size_t)320*HID2 + 16*nt + 4*q);
            const float4 v = make_float4(acc[nt].x, acc[nt].y, acc[nt].z, acc[nt].w);
            *(float4*)(d1 + 16*nt) = v;
            *(float4*)(d2 + 16*nt) = make_float4(v.x+w3.x, v.y+w3.y, v.z+w3.z, v.w+w3.w);
        }
    }
}

// ---------------- per-edge MFMA kernel ----------------
__global__ __launch_bounds__(256,4) void edge_kernel(
    const float* __restrict__ pos_mol, const float* __restrict__ pos_frag,
    const float* __restrict__ W1, const float* __restrict__ ln_g,
    const float* __restrict__ ln_b, const float* __restrict__ W2,
    const float* __restrict__ b2, const float* __restrict__ P,
    float* __restrict__ out)
{
    extern __shared__ unsigned sm[];
    unsigned* W1T = sm;                  // [256 ch][32 words], swizzled
    float*    pp  = (float*)(sm + 8192); // [256 ch][2] = (ln_g, ln_b)
    unsigned* a2p = sm + 8704;           // [8 ks][4 q][8 o] uint4 = 4KB
    const int tid = threadIdx.x, lane = tid & 63, wid = tid >> 6;
    const int c15 = lane & 15, q = lane >> 4;

    // ---- stage W1 rows 256..319 transposed (bf16 [ch][k=64]), swizzled ----
    {
        const float* colp = W1 + (size_t)256*HID2 + tid;
        const unsigned swzS = ((unsigned)(tid&3)<<2) ^ ((unsigned)((tid>>3)&1)<<4);
        #pragma unroll 4
        for (int k3 = 0; k3 < 16; ++k3) {
            const float a0 = colp[(4*k3+0)*HID2];
            const float a1 = colp[(4*k3+1)*HID2];
            const float a2 = colp[(4*k3+2)*HID2];
            const float a3 = colp[(4*k3+3)*HID2];
            const unsigned w = (unsigned)tid*32 + (((unsigned)(2*k3)) ^ swzS);
            *(uint2*)&W1T[w] = make_uint2(pk_bf16(a0, a1), pk_bf16(a2, a3));
        }
        pp[2*tid]   = ln_g[tid];
        pp[2*tid+1] = ln_b[tid];
        // W2^T A-fragment slots: tid = ks*32 + qq*8 + oo
        const int ks = tid >> 5, qq = (tid >> 3) & 3, oo = tid & 7;
        unsigned wds[4];
        #pragma unroll
        for (int j = 0; j < 4; ++j) {
            const float lo = W2[(size_t)(32*ks + 8*qq + 2*j    )*NET + oo];
            const float hi = W2[(size_t)(32*ks + 8*qq + 2*j + 1)*NET + oo];
            wds[j] = pk_bf16(lo, hi);
        }
        *(uint4*)&a2p[tid*4] = make_uint4(wds[0], wds[1], wds[2], wds[3]);
    }

    float4 b2v = make_float4(0.f,0.f,0.f,0.f);
    if (q < 2) b2v = ((const float4*)b2)[q];

    const float delta = 10.0f/63.0f;
    const float coeff = -0.5f/(delta*delta);
    const float cl2e  = coeff * 1.44269504088896340736f;
    const float qoff  = (8.0f*delta) * (float)q;

    // A-read swizzle & lane-const address parts (sigma rows)
    const unsigned szA = ((unsigned)(c15&3)<<2) ^ ((unsigned)((c15>>2)&1)<<4);
    const unsigned laneRow = (unsigned)(c15>>2)*256 + (unsigned)(c15&3)*32;
    const unsigned kt0 = ((unsigned)(4*q))      ^ szA;   // kc=0
    const unsigned kt1 = ((unsigned)(16 + 4*q)) ^ szA;   // kc=1
    const unsigned a2lane = ((unsigned)(q*8 + (c15 & 7)))*4;  // c15>=8 mirrors (D-rows 8..15 unused)
    __syncthreads();

    #pragma unroll 1
    for (int it = 0; it < 5; ++it) {
        const int tile = blockIdx.x*20 + it*4 + wid;
        const bool isff = (tile < TILES_FF);
        int arow, browbase;
        const float* pa; const float* Pa; const float* Pb;
        size_t obase;
        if (isff) {
            const int bg = tile >> 4, i = tile & 15;
            arow = bg*MAXF + i; browbase = bg*MAXF;
            pa = pos_frag + (size_t)arow*3;
            Pa = P + (size_t)(R_FA + arow)*HID2;
            Pb = P + (size_t)(R_BFF + browbase)*HID2;
            obase = (size_t)(tile << 4) * NET;
        } else {
            const int tt = tile - TILES_FF, bg = tt >> 6, m = tt & 63;
            arow = bg*NMOL + m; browbase = bg*MAXF;
            pa = pos_mol + (size_t)arow*3;
            Pa = P + (size_t)arow*HID2;
            Pb = P + (size_t)(R_BMF + browbase)*HID2;
            obase = (size_t)(E_FF + (tt << 4)) * NET;
        }

        // distance for this lane's edge (col = c15)
        const float* pb = pos_frag + (size_t)(browbase + c15)*3;
        const float dx = pa[0]-pb[0], dy = pa[1]-pb[1], dz = pa[2]-pb[2];
        const float d  = sqrtf(fmaf(dx,dx, fmaf(dy,dy, fmaf(dz,dz, 1e-12f))));
        const float dq = d - qoff;

        // g B-fragments in-register; slot i of chunk kc: k = 32*kc + 8q + i
        #define GSLOT(KK) ({ const float dd_ = dq - (float)(KK)*(10.0f/63.0f); \
                             exp2f(cl2e*dd_*dd_); })
        U4 gB0, gB1;
        {
            unsigned g0[4], g1[4];
            #pragma unroll
            for (int j = 0; j < 4; ++j) {
                g0[j] = pk_bf16(GSLOT(2*j),      GSLOT(2*j+1));
                g1[j] = pk_bf16(GSLOT(32+2*j),   GSLOT(32+2*j+1));
            }
            gB0.u = make_uint4(g0[0], g0[1], g0[2], g0[3]);
            gB1.u = make_uint4(g1[0], g1[1], g1[2], g1[3]);
        }
        #undef GSLOT

        // GEMM1 with sigma rows: acc[2a+b] holds channels 32a+8q+4b+(0..3)
        f32x4 acc[16];
        const float* PaQ = Pa + 8*q;
        const float* PbQ = Pb + (size_t)c15*HID2 + 8*q;
        #pragma unroll
        for (int nt = 0; nt < 16; ++nt) {
            const int ofs = 32*(nt>>1) + 4*(nt&1);             // + 8q in bases
            const unsigned wbase = laneRow + (unsigned)(1024*(nt>>1) + 128*(nt&1));
            U4 a1a, a1b;
            a1a.u = *(const uint4*)&W1T[wbase + kt0];
            a1b.u = *(const uint4*)&W1T[wbase + kt1];
            const float4 pa4 = *(const float4*)(PaQ + ofs);
            const float4 pb4 = *(const float4*)(PbQ + ofs);
            f32x4 c;
            c.x = pa4.x + pb4.x; c.y = pa4.y + pb4.y;
            c.z = pa4.z + pb4.z; c.w = pa4.w + pb4.w;
            c = __builtin_amdgcn_mfma_f32_16x16x32_bf16(a1a.b, gB0.b, c, 0, 0, 0);
            c = __builtin_amdgcn_mfma_f32_16x16x32_bf16(a1b.b, gB1.b, c, 0, 0, 0);
            acc[nt] = c;
        }

        // LayerNorm stats (lane holds 64 channels; reduce over q-lanes)
        float s1 = 0.f, s2 = 0.f;
        #pragma unroll
        for (int nt = 0; nt < 16; ++nt) {
            const f32x4 c = acc[nt];
            s1 += (c.x + c.y) + (c.z + c.w);
            s2  = fmaf(c.x,c.x, fmaf(c.y,c.y, fmaf(c.z,c.z, fmaf(c.w,c.w, s2))));
        }
        s1 += __shfl_xor(s1, 16, 64); s1 += __shfl_xor(s1, 32, 64);
        s2 += __shfl_xor(s2, 16, 64); s2 += __shfl_xor(s2, 32, 64);
        const float mu  = s1 * (1.f/HID2);
        const float var = fmaf(-mu, mu, s2 * (1.f/HID2));
        const float rs  = rsqrtf(var + 1e-5f);
        const float c0  = -mu * rs;

        // LN + ReLU + pack: acc pair (2a, 2a+1) IS GEMM2's B-frag chunk a;
        // A-frag comes from LDS (one b128 per k-step).
        f32x4 o2 = {0.f, 0.f, 0.f, 0.f};
        #pragma unroll
        for (int a = 0; a < 8; ++a) {
            unsigned hh[4];
            #pragma unroll
            for (int b = 0; b < 2; ++b) {
                const int nt = 2*a + b;
                const float* pq = pp + (32*a + 4*b + 8*q)*2;
                const float4 g01 = *(const float4*)pq;
                const float4 g23 = *(const float4*)(pq + 4);
                const f32x4 c = acc[nt];
                const float h0 = fmaxf(fmaf(fmaf(c.x, rs, c0), g01.x, g01.y), 0.f);
                const float h1 = fmaxf(fmaf(fmaf(c.y, rs, c0), g01.z, g01.w), 0.f);
                const float h2 = fmaxf(fmaf(fmaf(c.z, rs, c0), g23.x, g23.y), 0.f);
                const float h3 = fmaxf(fmaf(fmaf(c.w, rs, c0), g23.z, g23.w), 0.f);
                hh[2*b]   = pk_bf16(h0, h1);
                hh[2*b+1] = pk_bf16(h2, h3);
            }
            U4 a2u, b2u;
            a2u.u = *(const uint4*)&a2p[(unsigned)(a*128) + a2lane];
            b2u.u = make_uint4(hh[0], hh[1], hh[2], hh[3]);
            o2 = __builtin_amdgcn_mfma_f32_16x16x32_bf16(a2u.b, b2u.b, o2, 0, 0, 0);
        }

        // store: D rows 0..7 = outputs; lane (q<2, c15): edge c15, o = 4q+j
        if (lane < 32) {
            const float4 r = make_float4(o2.x + b2v.x, o2.y + b2v.y,
                                         o2.z + b2v.z, o2.w + b2v.w);
            *(float4*)(out + obase + (size_t)c15*NET + 4*q) = r;
        }
    }
}

extern "C" void kernel_launch(void* const* d_in, const int* in_sizes, int n_in,
                              void* d_out, int out_size, void* d_ws, size_t ws_size,
                              hipStream_t stream)
{
    const float* h_mol    = (const float*)d_in[0];
    const float* pos_mol  = (const float*)d_in[1];
    const float* h_frag   = (const float*)d_in[2];
    const float* pos_frag = (const float*)d_in[3];
    // d_in[4], d_in[5]: batch indices — contiguous per-graph layout, unused
    const float* W1   = (const float*)d_in[6];
    const float* b1   = (const float*)d_in[7];
    const float* ln_g = (const float*)d_in[8];
    const float* ln_b = (const float*)d_in[9];
    const float* W2   = (const float*)d_in[10];
    const float* b2   = (const float*)d_in[11];

    float* P    = (float*)d_ws;       // 28672 * 256 f32 = 29.36 MB
    float* outp = (float*)d_out;

    hipFuncSetAttribute((const void*)proj_kernel,
                        hipFuncAttributeMaxDynamicSharedMemorySize, PROJ_LDS_BYTES);
    proj_kernel<<<384, 256, PROJ_LDS_BYTES, stream>>>(h_mol, h_frag, W1, b1, P);

    edge_kernel<<<1024, 256, EDGE_LDS_BYTES, stream>>>(
        pos_mol, pos_frag, W1, ln_g, ln_b, W2, b2, P, outp);
}

// Round 8
// 477.946 us; speedup vs baseline: 1.1535x; 1.0082x over previous
//
#include <hip/hip_runtime.h>
#include <hip/hip_bf16.h>
#include <math.h>

// SimpleEdgePredictor on MI355X — R8 = R6 sigma-structure, register-pressure fix.
// R5/R6 lesson: launch_bounds(256,4) (cap 128 unified) forces acc spill
// (FETCH 767MB of scratch). R8: launch_bounds(256,3) -> cap ~170 (106 arch
// + 64 acc fits, no spill), 3 blocks/CU (vs R4's 2). GEMM1 runs from C=0 and
// the P_a/P_b adds are fused into the LN-stats pass (loads consumed where
// issued -> lower peak pressure). proj: 96 blocks x 4 node-groups so the
// 32KB W-tile staging is amortized 4x.

#define HID   128
#define HID2  256
#define NG    64
#define NET   8
#define NB    256
#define NMOL  64
#define MAXF  16

// P row layout (rows of 256 f32):
//   [0,16384) mol | [16384,20480) fa | [20480,24576) bff(+b1) | [24576,28672) bmf(+w320)
#define PMOL   16384
#define R_FA   16384
#define R_BFF  20480
#define R_BMF  24576

#define E_FF     65536
#define TILES_FF 4096
#define NTILES   20480

#define EDGE_LDS_WORDS (8192 + 512 + 1024)     // W1T + ln params + W2T frags
#define EDGE_LDS_BYTES (EDGE_LDS_WORDS*4)      // 38912
#define PROJ_LDS_BYTES (256*64*4)              // 65536

typedef float f32x4 __attribute__((ext_vector_type(4)));
typedef short bf16x8 __attribute__((ext_vector_type(8)));
union U4 { uint4 u; bf16x8 b; };

__device__ __forceinline__ unsigned pk_bf16(float lo, float hi) {
    __hip_bfloat162 h = __float22bfloat162_rn(float2{lo, hi});
    union { __hip_bfloat162 h; unsigned u; } c; c.h = h;
    return c.u;
}

// ---------------- proj: P[node] = h[node] @ Whalf (MFMA) ----------------
// 96 blocks: [0,64) mol | [64,80) frag-a | [80,96) frag-b (dual store);
// each block stages W once, then loops 4 node-groups of 64.
__global__ __launch_bounds__(256,2) void proj_kernel(
    const float* __restrict__ h_mol, const float* __restrict__ h_frag,
    const float* __restrict__ W1, const float* __restrict__ b1,
    float* __restrict__ P)
{
    extern __shared__ unsigned WT[];           // [256 ch][64 words], swizzled
    const int tid = threadIdx.x, lane = tid & 63, wid = tid >> 6;
    const int c15 = lane & 15, q = lane >> 4;
    const int blk = blockIdx.x;

    int wrow0, mode, base; const float* src; int dr0;
    if (blk < 64)       { mode=0; wrow0=0;   src=h_mol;  base = blk*256;       dr0 = base; }
    else if (blk < 80)  { mode=0; wrow0=0;   src=h_frag; base = (blk-64)*256;  dr0 = R_FA + base; }
    else                { mode=1; wrow0=HID; src=h_frag; base = (blk-80)*256;  dr0 = R_BFF + base; }

    // stage Whalf transposed -> bf16 [ch][k], swizzled; thread = column ch=tid
    {
        const float* colp = W1 + (size_t)wrow0*HID2 + tid;
        const unsigned swzS = ((unsigned)(tid&3)<<2) ^ ((unsigned)((tid>>3)&1)<<4);
        #pragma unroll 8
        for (int k2 = 0; k2 < 64; ++k2) {
            const float a0 = colp[(2*k2  )*HID2];
            const float a1 = colp[(2*k2+1)*HID2];
            WT[(unsigned)tid*64 + (((unsigned)k2) ^ swzS)] = pk_bf16(a0, a1);
        }
    }
    __syncthreads();

    const unsigned szA = ((unsigned)(c15&3)<<2) ^ ((unsigned)((c15>>3)&1)<<4);

    #pragma unroll 1
    for (int g = 0; g < 4; ++g) {
        const int nloc = base + g*64 + wid*16 + c15;   // this lane's node (column)
        const float* hp = src + (size_t)nloc*HID;

        // B-fragments: h[node][32kc+8q+i], i=0..7
        U4 bB[4];
        #pragma unroll
        for (int kc = 0; kc < 4; ++kc) {
            const float4 lo = *(const float4*)(hp + 32*kc + 8*q);
            const float4 hi = *(const float4*)(hp + 32*kc + 8*q + 4);
            bB[kc].u = make_uint4(pk_bf16(lo.x,lo.y), pk_bf16(lo.z,lo.w),
                                  pk_bf16(hi.x,hi.y), pk_bf16(hi.z,hi.w));
        }

        f32x4 acc[16];
        #pragma unroll
        for (int nt = 0; nt < 16; ++nt) {
            f32x4 c;
            if (mode == 1) {
                const float4 bi = *(const float4*)(b1 + 16*nt + 4*q);
                c.x = bi.x; c.y = bi.y; c.z = bi.z; c.w = bi.w;
            } else { c.x = 0.f; c.y = 0.f; c.z = 0.f; c.w = 0.f; }
            const unsigned rowbase = (unsigned)(16*nt + c15)*64;
            #pragma unroll
            for (int kc = 0; kc < 4; ++kc) {
                U4 a;
                a.u = *(const uint4*)&WT[rowbase + (((unsigned)(16*kc + 4*q)) ^ szA)];
                c = __builtin_amdgcn_mfma_f32_16x16x32_bf16(a.b, bB[kc].b, c, 0, 0, 0);
            }
            acc[nt] = c;
        }

        // store: lane(q,c15) reg j = channel 16nt+4q+j of node
        const int drow = dr0 + g*64 + wid*16 + c15;
        float* d1 = P + (size_t)drow*HID2 + 4*q;
        if (mode == 0) {
            #pragma unroll
            for (int nt = 0; nt < 16; ++nt)
                *(float4*)(d1 + 16*nt) = make_float4(acc[nt].x, acc[nt].y, acc[nt].z, acc[nt].w);
        } else {
            float* d2 = d1 + (size_t)4096*HID2;    // bmf twin
            #pragma unroll
            for (int nt = 0; nt < 16; ++nt) {
                const float4 w3 = *(const float4*)(W1 + (size_t)320*HID2 + 16*nt + 4*q);
                const float4 v = make_float4(acc[nt].x, acc[nt].y, acc[nt].z, acc[nt].w);
                *(float4*)(d1 + 16*nt) = v;
                *(float4*)(d2 + 16*nt) = make_float4(v.x+w3.x, v.y+w3.y, v.z+w3.z, v.w+w3.w);
            }
        }
    }
}

// ---------------- per-edge MFMA kernel ----------------
__global__ __launch_bounds__(256,3) void edge_kernel(
    const float* __restrict__ pos_mol, const float* __restrict__ pos_frag,
    const float* __restrict__ W1, const float* __restrict__ ln_g,
    const float* __restrict__ ln_b, const float* __restrict__ W2,
    const float* __restrict__ b2, const float* __restrict__ P,
    float* __restrict__ out)
{
    extern __shared__ unsigned sm[];
    unsigned* W1T = sm;                  // [256 ch][32 words], swizzled
    float*    pp  = (float*)(sm + 8192); // [256 ch][2] = (ln_g, ln_b)
    unsigned* a2p = sm + 8704;           // [8 ks][4 q][8 o] uint4 = 4KB
    const int tid = threadIdx.x, lane = tid & 63, wid = tid >> 6;
    const int c15 = lane & 15, q = lane >> 4;

    // ---- stage W1 rows 256..319 transposed (bf16 [ch][k=64]), swizzled ----
    {
        const float* colp = W1 + (size_t)256*HID2 + tid;
        const unsigned swzS = ((unsigned)(tid&3)<<2) ^ ((unsigned)((tid>>3)&1)<<4);
        #pragma unroll 4
        for (int k3 = 0; k3 < 16; ++k3) {
            const float a0 = colp[(4*k3+0)*HID2];
            const float a1 = colp[(4*k3+1)*HID2];
            const float a2 = colp[(4*k3+2)*HID2];
            const float a3 = colp[(4*k3+3)*HID2];
            const unsigned w = (unsigned)tid*32 + (((unsigned)(2*k3)) ^ swzS);
            *(uint2*)&W1T[w] = make_uint2(pk_bf16(a0, a1), pk_bf16(a2, a3));
        }
        pp[2*tid]   = ln_g[tid];
        pp[2*tid+1] = ln_b[tid];
        // W2^T A-fragment slots: tid = ks*32 + qq*8 + oo
        const int ks = tid >> 5, qq = (tid >> 3) & 3, oo = tid & 7;
        unsigned wds[4];
        #pragma unroll
        for (int j = 0; j < 4; ++j) {
            const float lo = W2[(size_t)(32*ks + 8*qq + 2*j    )*NET + oo];
            const float hi = W2[(size_t)(32*ks + 8*qq + 2*j + 1)*NET + oo];
            wds[j] = pk_bf16(lo, hi);
        }
        *(uint4*)&a2p[tid*4] = make_uint4(wds[0], wds[1], wds[2], wds[3]);
    }

    float4 b2v = make_float4(0.f,0.f,0.f,0.f);
    if (q < 2) b2v = ((const float4*)b2)[q];

    const float delta = 10.0f/63.0f;
    const float coeff = -0.5f/(delta*delta);
    const float cl2e  = coeff * 1.44269504088896340736f;
    const float qoff  = (8.0f*delta) * (float)q;

    // A-read swizzle & lane-const address parts (sigma rows)
    const unsigned szA = ((unsigned)(c15&3)<<2) ^ ((unsigned)((c15>>2)&1)<<4);
    const unsigned laneRow = (unsigned)(c15>>2)*256 + (unsigned)(c15&3)*32;
    const unsigned kt0 = ((unsigned)(4*q))      ^ szA;   // kc=0
    const unsigned kt1 = ((unsigned)(16 + 4*q)) ^ szA;   // kc=1
    const unsigned a2lane = ((unsigned)(q*8 + (c15 & 7)))*4;  // c15>=8 mirrors (D-rows 8..15 unused)
    __syncthreads();

    #pragma unroll 1
    for (int it = 0; it < 5; ++it) {
        const int tile = blockIdx.x*20 + it*4 + wid;
        const bool isff = (tile < TILES_FF);
        int arow, browbase;
        const float* pa; const float* Pa; const float* Pb;
        size_t obase;
        if (isff) {
            const int bg = tile >> 4, i = tile & 15;
            arow = bg*MAXF + i; browbase = bg*MAXF;
            pa = pos_frag + (size_t)arow*3;
            Pa = P + (size_t)(R_FA + arow)*HID2;
            Pb = P + (size_t)(R_BFF + browbase)*HID2;
            obase = (size_t)(tile << 4) * NET;
        } else {
            const int tt = tile - TILES_FF, bg = tt >> 6, m = tt & 63;
            arow = bg*NMOL + m; browbase = bg*MAXF;
            pa = pos_mol + (size_t)arow*3;
            Pa = P + (size_t)arow*HID2;
            Pb = P + (size_t)(R_BMF + browbase)*HID2;
            obase = (size_t)(E_FF + (tt << 4)) * NET;
        }

        // distance for this lane's edge (col = c15)
        const float* pb = pos_frag + (size_t)(browbase + c15)*3;
        const float dx = pa[0]-pb[0], dy = pa[1]-pb[1], dz = pa[2]-pb[2];
        const float d  = sqrtf(fmaf(dx,dx, fmaf(dy,dy, fmaf(dz,dz, 1e-12f))));
        const float dq = d - qoff;

        // g B-fragments in-register; slot i of chunk kc: k = 32*kc + 8q + i
        #define GSLOT(KK) ({ const float dd_ = dq - (float)(KK)*(10.0f/63.0f); \
                             exp2f(cl2e*dd_*dd_); })
        U4 gB0, gB1;
        {
            unsigned g0[4], g1[4];
            #pragma unroll
            for (int j = 0; j < 4; ++j) {
                g0[j] = pk_bf16(GSLOT(2*j),      GSLOT(2*j+1));
                g1[j] = pk_bf16(GSLOT(32+2*j),   GSLOT(32+2*j+1));
            }
            gB0.u = make_uint4(g0[0], g0[1], g0[2], g0[3]);
            gB1.u = make_uint4(g1[0], g1[1], g1[2], g1[3]);
        }
        #undef GSLOT

        // GEMM1 (pure LDS+MFMA, C=0): acc[2a+b] = smear part of channels
        // 32a+8q+4b+(0..3); P_a/P_b added in the stats pass below.
        f32x4 acc[16];
        #pragma unroll
        for (int nt = 0; nt < 16; ++nt) {
            const unsigned wbase = laneRow + (unsigned)(1024*(nt>>1) + 128*(nt&1));
            U4 a1a, a1b;
            a1a.u = *(const uint4*)&W1T[wbase + kt0];
            a1b.u = *(const uint4*)&W1T[wbase + kt1];
            f32x4 c = {0.f, 0.f, 0.f, 0.f};
            c = __builtin_amdgcn_mfma_f32_16x16x32_bf16(a1a.b, gB0.b, c, 0, 0, 0);
            c = __builtin_amdgcn_mfma_f32_16x16x32_bf16(a1b.b, gB1.b, c, 0, 0, 0);
            acc[nt] = c;
        }

        // P-add + LayerNorm stats (loads consumed where issued)
        float s1 = 0.f, s2 = 0.f;
        const float* PaQ = Pa + 8*q;
        const float* PbQ = Pb + (size_t)c15*HID2 + 8*q;
        #pragma unroll
        for (int nt = 0; nt < 16; ++nt) {
            const int ofs = 32*(nt>>1) + 4*(nt&1);
            const float4 pa4 = *(const float4*)(PaQ + ofs);
            const float4 pb4 = *(const float4*)(PbQ + ofs);
            f32x4 c = acc[nt];
            c.x += pa4.x + pb4.x; c.y += pa4.y + pb4.y;
            c.z += pa4.z + pb4.z; c.w += pa4.w + pb4.w;
            acc[nt] = c;
            s1 += (c.x + c.y) + (c.z + c.w);
            s2  = fmaf(c.x,c.x, fmaf(c.y,c.y, fmaf(c.z,c.z, fmaf(c.w,c.w, s2))));
        }
        s1 += __shfl_xor(s1, 16, 64); s1 += __shfl_xor(s1, 32, 64);
        s2 += __shfl_xor(s2, 16, 64); s2 += __shfl_xor(s2, 32, 64);
        const float mu  = s1 * (1.f/HID2);
        const float var = fmaf(-mu, mu, s2 * (1.f/HID2));
        const float rs  = rsqrtf(var + 1e-5f);
        const float c0  = -mu * rs;

        // LN + ReLU + pack: acc pair (2a, 2a+1) IS GEMM2's B-frag chunk a;
        // A-frag from LDS (one b128 per k-step).
        f32x4 o2 = {0.f, 0.f, 0.f, 0.f};
        #pragma unroll
        for (int a = 0; a < 8; ++a) {
            unsigned hh[4];
            #pragma unroll
            for (int b = 0; b < 2; ++b) {
                const int nt = 2*a + b;
                const float* pq = pp + (32*a + 4*b + 8*q)*2;
                const float4 g01 = *(const float4*)pq;
                const float4 g23 = *(const float4*)(pq + 4);
                const f32x4 c = acc[nt];
                const float h0 = fmaxf(fmaf(fmaf(c.x, rs, c0), g01.x, g01.y), 0.f);
                const float h1 = fmaxf(fmaf(fmaf(c.y, rs, c0), g01.z, g01.w), 0.f);
                const float h2 = fmaxf(fmaf(fmaf(c.z, rs, c0), g23.x, g23.y), 0.f);
                const float h3 = fmaxf(fmaf(fmaf(c.w, rs, c0), g23.z, g23.w), 0.f);
                hh[2*b]   = pk_bf16(h0, h1);
                hh[2*b+1] = pk_bf16(h2, h3);
            }
            U4 a2u, b2u;
            a2u.u = *(const uint4*)&a2p[(unsigned)(a*128) + a2lane];
            b2u.u = make_uint4(hh[0], hh[1], hh[2], hh[3]);
            o2 = __builtin_amdgcn_mfma_f32_16x16x32_bf16(a2u.b, b2u.b, o2, 0, 0, 0);
        }

        // store: D rows 0..7 = outputs; lane (q<2, c15): edge c15, o = 4q+j
        if (lane < 32) {
            const float4 r = make_float4(o2.x + b2v.x, o2.y + b2v.y,
                                         o2.z + b2v.z, o2.w + b2v.w);
            *(float4*)(out + obase + (size_t)c15*NET + 4*q) = r;
        }
    }
}

extern "C" void kernel_launch(void* const* d_in, const int* in_sizes, int n_in,
                              void* d_out, int out_size, void* d_ws, size_t ws_size,
                              hipStream_t stream)
{
    const float* h_mol    = (const float*)d_in[0];
    const float* pos_mol  = (const float*)d_in[1];
    const float* h_frag   = (const float*)d_in[2];
    const float* pos_frag = (const float*)d_in[3];
    // d_in[4], d_in[5]: batch indices — contiguous per-graph layout, unused
    const float* W1   = (const float*)d_in[6];
    const float* b1   = (const float*)d_in[7];
    const float* ln_g = (const float*)d_in[8];
    const float* ln_b = (const float*)d_in[9];
    const float* W2   = (const float*)d_in[10];
    const float* b2   = (const float*)d_in[11];

    float* P    = (float*)d_ws;       // 28672 * 256 f32 = 29.36 MB
    float* outp = (float*)d_out;

    hipFuncSetAttribute((const void*)proj_kernel,
                        hipFuncAttributeMaxDynamicSharedMemorySize, PROJ_LDS_BYTES);
    proj_kernel<<<96, 256, PROJ_LDS_BYTES, stream>>>(h_mol, h_frag, W1, b1, P);

    edge_kernel<<<1024, 256, EDGE_LDS_BYTES, stream>>>(
        pos_mol, pos_frag, W1, ln_g, ln_b, W2, b2, P, outp);
}

// Round 11
// 330.788 us; speedup vs baseline: 1.6666x; 1.4449x over previous
//
#include <hip/hip_runtime.h>
#include <hip/hip_bf16.h>
#include <math.h>

// SimpleEdgePredictor on MI355X — R9 = R8 structure, spill-free occupancy.
// Lesson R5-R8: scheduled demand ~190-250 unified regs; caps of 128/170
// (launch_bounds 4/3) turn occupancy into scratch spill (FETCH 700-870MB,
// 3-4x slower). R9: launch_bounds(256,2) (cap 256, R4-proven spill-free),
// 2 blocks/CU, keep sigma-structure wins (no hbuf/barriers, LDS a2p,
// fused P-adds). Proj: 384 blocks x 64 rows (full-machine TLP; 96-block
// version left 63% of CUs idle at 1 wave/SIMD).

#define HID   128
#define HID2  256
#define NG    64
#define NET   8
#define NB    256
#define NMOL  64
#define MAXF  16

// P row layout (rows of 256 f32):
//   [0,16384) mol | [16384,20480) fa | [20480,24576) bff(+b1) | [24576,28672) bmf(+w320)
#define PMOL   16384
#define R_FA   16384
#define R_BFF  20480
#define R_BMF  24576

#define E_FF     65536
#define TILES_FF 4096
#define NTILES   20480

#define EDGE_LDS_WORDS (8192 + 512 + 1024)     // W1T + ln params + W2T frags
#define EDGE_LDS_BYTES (EDGE_LDS_WORDS*4)      // 38912
#define PROJ_LDS_BYTES (256*64*4)              // 65536

typedef float f32x4 __attribute__((ext_vector_type(4)));
typedef short bf16x8 __attribute__((ext_vector_type(8)));
union U4 { uint4 u; bf16x8 b; };

__device__ __forceinline__ unsigned pk_bf16(float lo, float hi) {
    __hip_bfloat162 h = __float22bfloat162_rn(float2{lo, hi});
    union { __hip_bfloat162 h; unsigned u; } c; c.h = h;
    return c.u;
}

// ---------------- proj: P[node] = h[node] @ Whalf (MFMA) ----------------
// 384 blocks x 64 rows: [0,256) mol | [256,320) frag-a | [320,384) frag-b.
__global__ __launch_bounds__(256,2) void proj_kernel(
    const float* __restrict__ h_mol, const float* __restrict__ h_frag,
    const float* __restrict__ W1, const float* __restrict__ b1,
    float* __restrict__ P)
{
    extern __shared__ unsigned WT[];           // [256 ch][64 words], swizzled
    const int tid = threadIdx.x, lane = tid & 63, wid = tid >> 6;
    const int c15 = lane & 15, q = lane >> 4;
    const int blk = blockIdx.x;

    int wrow0, mode, base; const float* src; int dr0;
    if (blk < 256)      { mode=0; wrow0=0;   src=h_mol;  base = blk*64;        dr0 = base; }
    else if (blk < 320) { mode=0; wrow0=0;   src=h_frag; base = (blk-256)*64;  dr0 = R_FA + base; }
    else                { mode=1; wrow0=HID; src=h_frag; base = (blk-320)*64;  dr0 = R_BFF + base; }

    // stage Whalf transposed -> bf16 [ch][k], swizzled; thread = column ch=tid
    {
        const float* colp = W1 + (size_t)wrow0*HID2 + tid;
        const unsigned swzS = ((unsigned)(tid&3)<<2) ^ ((unsigned)((tid>>3)&1)<<4);
        #pragma unroll 8
        for (int k2 = 0; k2 < 64; ++k2) {
            const float a0 = colp[(2*k2  )*HID2];
            const float a1 = colp[(2*k2+1)*HID2];
            WT[(unsigned)tid*64 + (((unsigned)k2) ^ swzS)] = pk_bf16(a0, a1);
        }
    }
    __syncthreads();

    const unsigned szA = ((unsigned)(c15&3)<<2) ^ ((unsigned)((c15>>3)&1)<<4);

    const int nloc = base + wid*16 + c15;      // this lane's node (column)
    const float* hp = src + (size_t)nloc*HID;

    // B-fragments: h[node][32kc+8q+i], i=0..7
    U4 bB[4];
    #pragma unroll
    for (int kc = 0; kc < 4; ++kc) {
        const float4 lo = *(const float4*)(hp + 32*kc + 8*q);
        const float4 hi = *(const float4*)(hp + 32*kc + 8*q + 4);
        bB[kc].u = make_uint4(pk_bf16(lo.x,lo.y), pk_bf16(lo.z,lo.w),
                              pk_bf16(hi.x,hi.y), pk_bf16(hi.z,hi.w));
    }

    f32x4 acc[16];
    #pragma unroll
    for (int nt = 0; nt < 16; ++nt) {
        f32x4 c;
        if (mode == 1) {
            const float4 bi = *(const float4*)(b1 + 16*nt + 4*q);
            c.x = bi.x; c.y = bi.y; c.z = bi.z; c.w = bi.w;
        } else { c.x = 0.f; c.y = 0.f; c.z = 0.f; c.w = 0.f; }
        const unsigned rowbase = (unsigned)(16*nt + c15)*64;
        #pragma unroll
        for (int kc = 0; kc < 4; ++kc) {
            U4 a;
            a.u = *(const uint4*)&WT[rowbase + (((unsigned)(16*kc + 4*q)) ^ szA)];
            c = __builtin_amdgcn_mfma_f32_16x16x32_bf16(a.b, bB[kc].b, c, 0, 0, 0);
        }
        acc[nt] = c;
    }

    // store: lane(q,c15) reg j = channel 16nt+4q+j of node
    const int drow = dr0 + wid*16 + c15;
    float* d1 = P + (size_t)drow*HID2 + 4*q;
    if (mode == 0) {
        #pragma unroll
        for (int nt = 0; nt < 16; ++nt)
            *(float4*)(d1 + 16*nt) = make_float4(acc[nt].x, acc[nt].y, acc[nt].z, acc[nt].w);
    } else {
        float* d2 = d1 + (size_t)4096*HID2;    // bmf twin
        #pragma unroll
        for (int nt = 0; nt < 16; ++nt) {
            const float4 w3 = *(const float4*)(W1 + (size_t)320*HID2 + 16*nt + 4*q);
            const float4 v = make_float4(acc[nt].x, acc[nt].y, acc[nt].z, acc[nt].w);
            *(float4*)(d1 + 16*nt) = v;
            *(float4*)(d2 + 16*nt) = make_float4(v.x+w3.x, v.y+w3.y, v.z+w3.z, v.w+w3.w);
        }
    }
}

// ---------------- per-edge MFMA kernel ----------------
__global__ __launch_bounds__(256,2) void edge_kernel(
    const float* __restrict__ pos_mol, const float* __restrict__ pos_frag,
    const float* __restrict__ W1, const float* __restrict__ ln_g,
    const float* __restrict__ ln_b, const float* __restrict__ W2,
    const float* __restrict__ b2, const float* __restrict__ P,
    float* __restrict__ out)
{
    extern __shared__ unsigned sm[];
    unsigned* W1T = sm;                  // [256 ch][32 words], swizzled
    float*    pp  = (float*)(sm + 8192); // [256 ch][2] = (ln_g, ln_b)
    unsigned* a2p = sm + 8704;           // [8 ks][4 q][8 o] uint4 = 4KB
    const int tid = threadIdx.x, lane = tid & 63, wid = tid >> 6;
    const int c15 = lane & 15, q = lane >> 4;

    // ---- stage W1 rows 256..319 transposed (bf16 [ch][k=64]), swizzled ----
    {
        const float* colp = W1 + (size_t)256*HID2 + tid;
        const unsigned swzS = ((unsigned)(tid&3)<<2) ^ ((unsigned)((tid>>3)&1)<<4);
        #pragma unroll 4
        for (int k3 = 0; k3 < 16; ++k3) {
            const float a0 = colp[(4*k3+0)*HID2];
            const float a1 = colp[(4*k3+1)*HID2];
            const float a2 = colp[(4*k3+2)*HID2];
            const float a3 = colp[(4*k3+3)*HID2];
            const unsigned w = (unsigned)tid*32 + (((unsigned)(2*k3)) ^ swzS);
            *(uint2*)&W1T[w] = make_uint2(pk_bf16(a0, a1), pk_bf16(a2, a3));
        }
        pp[2*tid]   = ln_g[tid];
        pp[2*tid+1] = ln_b[tid];
        // W2^T A-fragment slots: tid = ks*32 + qq*8 + oo
        const int ks = tid >> 5, qq = (tid >> 3) & 3, oo = tid & 7;
        unsigned wds[4];
        #pragma unroll
        for (int j = 0; j < 4; ++j) {
            const float lo = W2[(size_t)(32*ks + 8*qq + 2*j    )*NET + oo];
            const float hi = W2[(size_t)(32*ks + 8*qq + 2*j + 1)*NET + oo];
            wds[j] = pk_bf16(lo, hi);
        }
        *(uint4*)&a2p[tid*4] = make_uint4(wds[0], wds[1], wds[2], wds[3]);
    }

    float4 b2v = make_float4(0.f,0.f,0.f,0.f);
    if (q < 2) b2v = ((const float4*)b2)[q];

    const float delta = 10.0f/63.0f;
    const float coeff = -0.5f/(delta*delta);
    const float cl2e  = coeff * 1.44269504088896340736f;
    const float qoff  = (8.0f*delta) * (float)q;

    // A-read swizzle & lane-const address parts (sigma rows)
    const unsigned szA = ((unsigned)(c15&3)<<2) ^ ((unsigned)((c15>>2)&1)<<4);
    const unsigned laneRow = (unsigned)(c15>>2)*256 + (unsigned)(c15&3)*32;
    const unsigned kt0 = ((unsigned)(4*q))      ^ szA;   // kc=0
    const unsigned kt1 = ((unsigned)(16 + 4*q)) ^ szA;   // kc=1
    const unsigned a2lane = ((unsigned)(q*8 + (c15 & 7)))*4;  // c15>=8 mirrors (D-rows 8..15 unused)
    __syncthreads();

    #pragma unroll 1
    for (int it = 0; it < 5; ++it) {
        const int tile = blockIdx.x*20 + it*4 + wid;
        const bool isff = (tile < TILES_FF);
        int arow, browbase;
        const float* pa; const float* Pa; const float* Pb;
        size_t obase;
        if (isff) {
            const int bg = tile >> 4, i = tile & 15;
            arow = bg*MAXF + i; browbase = bg*MAXF;
            pa = pos_frag + (size_t)arow*3;
            Pa = P + (size_t)(R_FA + arow)*HID2;
            Pb = P + (size_t)(R_BFF + browbase)*HID2;
            obase = (size_t)(tile << 4) * NET;
        } else {
            const int tt = tile - TILES_FF, bg = tt >> 6, m = tt & 63;
            arow = bg*NMOL + m; browbase = bg*MAXF;
            pa = pos_mol + (size_t)arow*3;
            Pa = P + (size_t)arow*HID2;
            Pb = P + (size_t)(R_BMF + browbase)*HID2;
            obase = (size_t)(E_FF + (tt << 4)) * NET;
        }

        // distance for this lane's edge (col = c15)
        const float* pb = pos_frag + (size_t)(browbase + c15)*3;
        const float dx = pa[0]-pb[0], dy = pa[1]-pb[1], dz = pa[2]-pb[2];
        const float d  = sqrtf(fmaf(dx,dx, fmaf(dy,dy, fmaf(dz,dz, 1e-12f))));
        const float dq = d - qoff;

        // g B-fragments in-register; slot i of chunk kc: k = 32*kc + 8q + i
        #define GSLOT(KK) ({ const float dd_ = dq - (float)(KK)*(10.0f/63.0f); \
                             exp2f(cl2e*dd_*dd_); })
        U4 gB0, gB1;
        {
            unsigned g0[4], g1[4];
            #pragma unroll
            for (int j = 0; j < 4; ++j) {
                g0[j] = pk_bf16(GSLOT(2*j),      GSLOT(2*j+1));
                g1[j] = pk_bf16(GSLOT(32+2*j),   GSLOT(32+2*j+1));
            }
            gB0.u = make_uint4(g0[0], g0[1], g0[2], g0[3]);
            gB1.u = make_uint4(g1[0], g1[1], g1[2], g1[3]);
        }
        #undef GSLOT

        // GEMM1 (pure LDS+MFMA, C=0): acc[2a+b] = smear part of channels
        // 32a+8q+4b+(0..3); P_a/P_b added in the stats pass below.
        f32x4 acc[16];
        #pragma unroll
        for (int nt = 0; nt < 16; ++nt) {
            const unsigned wbase = laneRow + (unsigned)(1024*(nt>>1) + 128*(nt&1));
            U4 a1a, a1b;
            a1a.u = *(const uint4*)&W1T[wbase + kt0];
            a1b.u = *(const uint4*)&W1T[wbase + kt1];
            f32x4 c = {0.f, 0.f, 0.f, 0.f};
            c = __builtin_amdgcn_mfma_f32_16x16x32_bf16(a1a.b, gB0.b, c, 0, 0, 0);
            c = __builtin_amdgcn_mfma_f32_16x16x32_bf16(a1b.b, gB1.b, c, 0, 0, 0);
            acc[nt] = c;
        }

        // P-add + LayerNorm stats (loads consumed where issued)
        float s1 = 0.f, s2 = 0.f;
        const float* PaQ = Pa + 8*q;
        const float* PbQ = Pb + (size_t)c15*HID2 + 8*q;
        #pragma unroll
        for (int nt = 0; nt < 16; ++nt) {
            const int ofs = 32*(nt>>1) + 4*(nt&1);
            const float4 pa4 = *(const float4*)(PaQ + ofs);
            const float4 pb4 = *(const float4*)(PbQ + ofs);
            f32x4 c = acc[nt];
            c.x += pa4.x + pb4.x; c.y += pa4.y + pb4.y;
            c.z += pa4.z + pb4.z; c.w += pa4.w + pb4.w;
            acc[nt] = c;
            s1 += (c.x + c.y) + (c.z + c.w);
            s2  = fmaf(c.x,c.x, fmaf(c.y,c.y, fmaf(c.z,c.z, fmaf(c.w,c.w, s2))));
        }
        s1 += __shfl_xor(s1, 16, 64); s1 += __shfl_xor(s1, 32, 64);
        s2 += __shfl_xor(s2, 16, 64); s2 += __shfl_xor(s2, 32, 64);
        const float mu  = s1 * (1.f/HID2);
        const float var = fmaf(-mu, mu, s2 * (1.f/HID2));
        const float rs  = rsqrtf(var + 1e-5f);
        const float c0  = -mu * rs;

        // LN + ReLU + pack: acc pair (2a, 2a+1) IS GEMM2's B-frag chunk a;
        // A-frag from LDS (one b128 per k-step).
        f32x4 o2 = {0.f, 0.f, 0.f, 0.f};
        #pragma unroll
        for (int a = 0; a < 8; ++a) {
            unsigned hh[4];
            #pragma unroll
            for (int b = 0; b < 2; ++b) {
                const int nt = 2*a + b;
                const float* pq = pp + (32*a + 4*b + 8*q)*2;
                const float4 g01 = *(const float4*)pq;
                const float4 g23 = *(const float4*)(pq + 4);
                const f32x4 c = acc[nt];
                const float h0 = fmaxf(fmaf(fmaf(c.x, rs, c0), g01.x, g01.y), 0.f);
                const float h1 = fmaxf(fmaf(fmaf(c.y, rs, c0), g01.z, g01.w), 0.f);
                const float h2 = fmaxf(fmaf(fmaf(c.z, rs, c0), g23.x, g23.y), 0.f);
                const float h3 = fmaxf(fmaf(fmaf(c.w, rs, c0), g23.z, g23.w), 0.f);
                hh[2*b]   = pk_bf16(h0, h1);
                hh[2*b+1] = pk_bf16(h2, h3);
            }
            U4 a2u, b2u;
            a2u.u = *(const uint4*)&a2p[(unsigned)(a*128) + a2lane];
            b2u.u = make_uint4(hh[0], hh[1], hh[2], hh[3]);
            o2 = __builtin_amdgcn_mfma_f32_16x16x32_bf16(a2u.b, b2u.b, o2, 0, 0, 0);
        }

        // store: D rows 0..7 = outputs; lane (q<2, c15): edge c15, o = 4q+j
        if (lane < 32) {
            const float4 r = make_float4(o2.x + b2v.x, o2.y + b2v.y,
                                         o2.z + b2v.z, o2.w + b2v.w);
            *(float4*)(out + obase + (size_t)c15*NET + 4*q) = r;
        }
    }
}

extern "C" void kernel_launch(void* const* d_in, const int* in_sizes, int n_in,
                              void* d_out, int out_size, void* d_ws, size_t ws_size,
                              hipStream_t stream)
{
    const float* h_mol    = (const float*)d_in[0];
    const float* pos_mol  = (const float*)d_in[1];
    const float* h_frag   = (const float*)d_in[2];
    const float* pos_frag = (const float*)d_in[3];
    // d_in[4], d_in[5]: batch indices — contiguous per-graph layout, unused
    const float* W1   = (const float*)d_in[6];
    const float* b1   = (const float*)d_in[7];
    const float* ln_g = (const float*)d_in[8];
    const float* ln_b = (const float*)d_in[9];
    const float* W2   = (const float*)d_in[10];
    const float* b2   = (const float*)d_in[11];

    float* P    = (float*)d_ws;       // 28672 * 256 f32 = 29.36 MB
    float* outp = (float*)d_out;

    hipFuncSetAttribute((const void*)proj_kernel,
                        hipFuncAttributeMaxDynamicSharedMemorySize, PROJ_LDS_BYTES);
    proj_kernel<<<384, 256, PROJ_LDS_BYTES, stream>>>(h_mol, h_frag, W1, b1, P);

    edge_kernel<<<1024, 256, EDGE_LDS_BYTES, stream>>>(
        pos_mol, pos_frag, W1, ln_g, ln_b, W2, b2, P, outp);
}

// Round 12
// 160.522 us; speedup vs baseline: 3.4344x; 2.0607x over previous
//
#include <hip/hip_runtime.h>
#include <hip/hip_bf16.h>
#include <math.h>

// SimpleEdgePredictor on MI355X — R12 = sigma-structure + R4-proven dataflow.
// R11 post-mortem: deferring P-adds out of GEMM1 + removing all barriers let
// the scheduler hoist 32 float4 P-loads (128 VGPRs) across iterations ->
// spill even at cap 256 (FETCH 490MB). R12: P-adds back in GEMM1 C-init
// (load->add->mfma, consumed immediately; R4 measured 21MB FETCH) and a
// sched_barrier(0) per tile-iteration to fence cross-iteration pipelining.

#define HID   128
#define HID2  256
#define NG    64
#define NET   8
#define NB    256
#define NMOL  64
#define MAXF  16

// P row layout (rows of 256 f32):
//   [0,16384) mol | [16384,20480) fa | [20480,24576) bff(+b1) | [24576,28672) bmf(+w320)
#define PMOL   16384
#define R_FA   16384
#define R_BFF  20480
#define R_BMF  24576

#define E_FF     65536
#define TILES_FF 4096
#define NTILES   20480

#define EDGE_LDS_WORDS (8192 + 512 + 1024)     // W1T + ln params + W2T frags
#define EDGE_LDS_BYTES (EDGE_LDS_WORDS*4)      // 38912
#define PROJ_LDS_BYTES (256*64*4)              // 65536

typedef float f32x4 __attribute__((ext_vector_type(4)));
typedef short bf16x8 __attribute__((ext_vector_type(8)));
union U4 { uint4 u; bf16x8 b; };

__device__ __forceinline__ unsigned pk_bf16(float lo, float hi) {
    __hip_bfloat162 h = __float22bfloat162_rn(float2{lo, hi});
    union { __hip_bfloat162 h; unsigned u; } c; c.h = h;
    return c.u;
}

// ---------------- proj: P[node] = h[node] @ Whalf (MFMA) ----------------
// 384 blocks x 64 rows: [0,256) mol | [256,320) frag-a | [320,384) frag-b.
__global__ __launch_bounds__(256,2) void proj_kernel(
    const float* __restrict__ h_mol, const float* __restrict__ h_frag,
    const float* __restrict__ W1, const float* __restrict__ b1,
    float* __restrict__ P)
{
    extern __shared__ unsigned WT[];           // [256 ch][64 words], swizzled
    const int tid = threadIdx.x, lane = tid & 63, wid = tid >> 6;
    const int c15 = lane & 15, q = lane >> 4;
    const int blk = blockIdx.x;

    int wrow0, mode, base; const float* src; int dr0;
    if (blk < 256)      { mode=0; wrow0=0;   src=h_mol;  base = blk*64;        dr0 = base; }
    else if (blk < 320) { mode=0; wrow0=0;   src=h_frag; base = (blk-256)*64;  dr0 = R_FA + base; }
    else                { mode=1; wrow0=HID; src=h_frag; base = (blk-320)*64;  dr0 = R_BFF + base; }

    // stage Whalf transposed -> bf16 [ch][k], swizzled; thread = column ch=tid
    {
        const float* colp = W1 + (size_t)wrow0*HID2 + tid;
        const unsigned swzS = ((unsigned)(tid&3)<<2) ^ ((unsigned)((tid>>3)&1)<<4);
        #pragma unroll 8
        for (int k2 = 0; k2 < 64; ++k2) {
            const float a0 = colp[(2*k2  )*HID2];
            const float a1 = colp[(2*k2+1)*HID2];
            WT[(unsigned)tid*64 + (((unsigned)k2) ^ swzS)] = pk_bf16(a0, a1);
        }
    }
    __syncthreads();

    const unsigned szA = ((unsigned)(c15&3)<<2) ^ ((unsigned)((c15>>3)&1)<<4);

    const int nloc = base + wid*16 + c15;      // this lane's node (column)
    const float* hp = src + (size_t)nloc*HID;

    // B-fragments: h[node][32kc+8q+i], i=0..7
    U4 bB[4];
    #pragma unroll
    for (int kc = 0; kc < 4; ++kc) {
        const float4 lo = *(const float4*)(hp + 32*kc + 8*q);
        const float4 hi = *(const float4*)(hp + 32*kc + 8*q + 4);
        bB[kc].u = make_uint4(pk_bf16(lo.x,lo.y), pk_bf16(lo.z,lo.w),
                              pk_bf16(hi.x,hi.y), pk_bf16(hi.z,hi.w));
    }

    f32x4 acc[16];
    #pragma unroll
    for (int nt = 0; nt < 16; ++nt) {
        f32x4 c;
        if (mode == 1) {
            const float4 bi = *(const float4*)(b1 + 16*nt + 4*q);
            c.x = bi.x; c.y = bi.y; c.z = bi.z; c.w = bi.w;
        } else { c.x = 0.f; c.y = 0.f; c.z = 0.f; c.w = 0.f; }
        const unsigned rowbase = (unsigned)(16*nt + c15)*64;
        #pragma unroll
        for (int kc = 0; kc < 4; ++kc) {
            U4 a;
            a.u = *(const uint4*)&WT[rowbase + (((unsigned)(16*kc + 4*q)) ^ szA)];
            c = __builtin_amdgcn_mfma_f32_16x16x32_bf16(a.b, bB[kc].b, c, 0, 0, 0);
        }
        acc[nt] = c;
    }

    // store: lane(q,c15) reg j = channel 16nt+4q+j of node
    const int drow = dr0 + wid*16 + c15;
    float* d1 = P + (size_t)drow*HID2 + 4*q;
    if (mode == 0) {
        #pragma unroll
        for (int nt = 0; nt < 16; ++nt)
            *(float4*)(d1 + 16*nt) = make_float4(acc[nt].x, acc[nt].y, acc[nt].z, acc[nt].w);
    } else {
        float* d2 = d1 + (size_t)4096*HID2;    // bmf twin
        #pragma unroll
        for (int nt = 0; nt < 16; ++nt) {
            const float4 w3 = *(const float4*)(W1 + (size_t)320*HID2 + 16*nt + 4*q);
            const float4 v = make_float4(acc[nt].x, acc[nt].y, acc[nt].z, acc[nt].w);
            *(float4*)(d1 + 16*nt) = v;
            *(float4*)(d2 + 16*nt) = make_float4(v.x+w3.x, v.y+w3.y, v.z+w3.z, v.w+w3.w);
        }
    }
}

// ---------------- per-edge MFMA kernel ----------------
__global__ __launch_bounds__(256,2) void edge_kernel(
    const float* __restrict__ pos_mol, const float* __restrict__ pos_frag,
    const float* __restrict__ W1, const float* __restrict__ ln_g,
    const float* __restrict__ ln_b, const float* __restrict__ W2,
    const float* __restrict__ b2, const float* __restrict__ P,
    float* __restrict__ out)
{
    extern __shared__ unsigned sm[];
    unsigned* W1T = sm;                  // [256 ch][32 words], swizzled
    float*    pp  = (float*)(sm + 8192); // [256 ch][2] = (ln_g, ln_b)
    unsigned* a2p = sm + 8704;           // [8 ks][4 q][8 o] uint4 = 4KB
    const int tid = threadIdx.x, lane = tid & 63, wid = tid >> 6;
    const int c15 = lane & 15, q = lane >> 4;

    // ---- stage W1 rows 256..319 transposed (bf16 [ch][k=64]), swizzled ----
    {
        const float* colp = W1 + (size_t)256*HID2 + tid;
        const unsigned swzS = ((unsigned)(tid&3)<<2) ^ ((unsigned)((tid>>3)&1)<<4);
        #pragma unroll 4
        for (int k3 = 0; k3 < 16; ++k3) {
            const float a0 = colp[(4*k3+0)*HID2];
            const float a1 = colp[(4*k3+1)*HID2];
            const float a2 = colp[(4*k3+2)*HID2];
            const float a3 = colp[(4*k3+3)*HID2];
            const unsigned w = (unsigned)tid*32 + (((unsigned)(2*k3)) ^ swzS);
            *(uint2*)&W1T[w] = make_uint2(pk_bf16(a0, a1), pk_bf16(a2, a3));
        }
        pp[2*tid]   = ln_g[tid];
        pp[2*tid+1] = ln_b[tid];
        // W2^T A-fragment slots: tid = ks*32 + qq*8 + oo
        const int ks = tid >> 5, qq = (tid >> 3) & 3, oo = tid & 7;
        unsigned wds[4];
        #pragma unroll
        for (int j = 0; j < 4; ++j) {
            const float lo = W2[(size_t)(32*ks + 8*qq + 2*j    )*NET + oo];
            const float hi = W2[(size_t)(32*ks + 8*qq + 2*j + 1)*NET + oo];
            wds[j] = pk_bf16(lo, hi);
        }
        *(uint4*)&a2p[tid*4] = make_uint4(wds[0], wds[1], wds[2], wds[3]);
    }

    float4 b2v = make_float4(0.f,0.f,0.f,0.f);
    if (q < 2) b2v = ((const float4*)b2)[q];

    const float delta = 10.0f/63.0f;
    const float coeff = -0.5f/(delta*delta);
    const float cl2e  = coeff * 1.44269504088896340736f;
    const float qoff  = (8.0f*delta) * (float)q;

    // A-read swizzle & lane-const address parts (sigma rows)
    const unsigned szA = ((unsigned)(c15&3)<<2) ^ ((unsigned)((c15>>2)&1)<<4);
    const unsigned laneRow = (unsigned)(c15>>2)*256 + (unsigned)(c15&3)*32;
    const unsigned kt0 = ((unsigned)(4*q))      ^ szA;   // kc=0
    const unsigned kt1 = ((unsigned)(16 + 4*q)) ^ szA;   // kc=1
    const unsigned a2lane = ((unsigned)(q*8 + (c15 & 7)))*4;  // c15>=8 mirrors (D-rows 8..15 unused)
    __syncthreads();

    #pragma unroll 1
    for (int it = 0; it < 5; ++it) {
        // fence: no instruction motion across tile iterations (prevents the
        // scheduler hoisting next tile's 32 P-loads over this tile's epilogue)
        __builtin_amdgcn_sched_barrier(0);

        const int tile = blockIdx.x*20 + it*4 + wid;
        const bool isff = (tile < TILES_FF);
        int arow, browbase;
        const float* pa; const float* Pa; const float* Pb;
        size_t obase;
        if (isff) {
            const int bg = tile >> 4, i = tile & 15;
            arow = bg*MAXF + i; browbase = bg*MAXF;
            pa = pos_frag + (size_t)arow*3;
            Pa = P + (size_t)(R_FA + arow)*HID2;
            Pb = P + (size_t)(R_BFF + browbase)*HID2;
            obase = (size_t)(tile << 4) * NET;
        } else {
            const int tt = tile - TILES_FF, bg = tt >> 6, m = tt & 63;
            arow = bg*NMOL + m; browbase = bg*MAXF;
            pa = pos_mol + (size_t)arow*3;
            Pa = P + (size_t)arow*HID2;
            Pb = P + (size_t)(R_BMF + browbase)*HID2;
            obase = (size_t)(E_FF + (tt << 4)) * NET;
        }

        // distance for this lane's edge (col = c15)
        const float* pb = pos_frag + (size_t)(browbase + c15)*3;
        const float dx = pa[0]-pb[0], dy = pa[1]-pb[1], dz = pa[2]-pb[2];
        const float d  = sqrtf(fmaf(dx,dx, fmaf(dy,dy, fmaf(dz,dz, 1e-12f))));
        const float dq = d - qoff;

        // g B-fragments in-register; slot i of chunk kc: k = 32*kc + 8q + i
        #define GSLOT(KK) ({ const float dd_ = dq - (float)(KK)*(10.0f/63.0f); \
                             exp2f(cl2e*dd_*dd_); })
        U4 gB0, gB1;
        {
            unsigned g0[4], g1[4];
            #pragma unroll
            for (int j = 0; j < 4; ++j) {
                g0[j] = pk_bf16(GSLOT(2*j),      GSLOT(2*j+1));
                g1[j] = pk_bf16(GSLOT(32+2*j),   GSLOT(32+2*j+1));
            }
            gB0.u = make_uint4(g0[0], g0[1], g0[2], g0[3]);
            gB1.u = make_uint4(g1[0], g1[1], g1[2], g1[3]);
        }
        #undef GSLOT

        // GEMM1 with sigma rows, C-init = P_a + P_b (loads consumed where
        // issued — R4-proven low-pressure form). acc[2a+b] holds channels
        // 32a+8q+4b+(0..3) of edge c15.
        f32x4 acc[16];
        const float* PaQ = Pa + 8*q;
        const float* PbQ = Pb + (size_t)c15*HID2 + 8*q;
        #pragma unroll
        for (int nt = 0; nt < 16; ++nt) {
            const int ofs = 32*(nt>>1) + 4*(nt&1);
            const unsigned wbase = laneRow + (unsigned)(1024*(nt>>1) + 128*(nt&1));
            U4 a1a, a1b;
            a1a.u = *(const uint4*)&W1T[wbase + kt0];
            a1b.u = *(const uint4*)&W1T[wbase + kt1];
            const float4 pa4 = *(const float4*)(PaQ + ofs);
            const float4 pb4 = *(const float4*)(PbQ + ofs);
            f32x4 c;
            c.x = pa4.x + pb4.x; c.y = pa4.y + pb4.y;
            c.z = pa4.z + pb4.z; c.w = pa4.w + pb4.w;
            c = __builtin_amdgcn_mfma_f32_16x16x32_bf16(a1a.b, gB0.b, c, 0, 0, 0);
            c = __builtin_amdgcn_mfma_f32_16x16x32_bf16(a1b.b, gB1.b, c, 0, 0, 0);
            acc[nt] = c;
        }

        // LayerNorm stats (lane holds 64 channels; reduce over q-lanes)
        float s1 = 0.f, s2 = 0.f;
        #pragma unroll
        for (int nt = 0; nt < 16; ++nt) {
            const f32x4 c = acc[nt];
            s1 += (c.x + c.y) + (c.z + c.w);
            s2  = fmaf(c.x,c.x, fmaf(c.y,c.y, fmaf(c.z,c.z, fmaf(c.w,c.w, s2))));
        }
        s1 += __shfl_xor(s1, 16, 64); s1 += __shfl_xor(s1, 32, 64);
        s2 += __shfl_xor(s2, 16, 64); s2 += __shfl_xor(s2, 32, 64);
        const float mu  = s1 * (1.f/HID2);
        const float var = fmaf(-mu, mu, s2 * (1.f/HID2));
        const float rs  = rsqrtf(var + 1e-5f);
        const float c0  = -mu * rs;

        // LN + ReLU + pack: acc pair (2a, 2a+1) IS GEMM2's B-frag chunk a;
        // A-frag from LDS (one b128 per k-step).
        f32x4 o2 = {0.f, 0.f, 0.f, 0.f};
        #pragma unroll
        for (int a = 0; a < 8; ++a) {
            unsigned hh[4];
            #pragma unroll
            for (int b = 0; b < 2; ++b) {
                const int nt = 2*a + b;
                const float* pq = pp + (32*a + 4*b + 8*q)*2;
                const float4 g01 = *(const float4*)pq;
                const float4 g23 = *(const float4*)(pq + 4);
                const f32x4 c = acc[nt];
                const float h0 = fmaxf(fmaf(fmaf(c.x, rs, c0), g01.x, g01.y), 0.f);
                const float h1 = fmaxf(fmaf(fmaf(c.y, rs, c0), g01.z, g01.w), 0.f);
                const float h2 = fmaxf(fmaf(fmaf(c.z, rs, c0), g23.x, g23.y), 0.f);
                const float h3 = fmaxf(fmaf(fmaf(c.w, rs, c0), g23.z, g23.w), 0.f);
                hh[2*b]   = pk_bf16(h0, h1);
                hh[2*b+1] = pk_bf16(h2, h3);
            }
            U4 a2u, b2u;
            a2u.u = *(const uint4*)&a2p[(unsigned)(a*128) + a2lane];
            b2u.u = make_uint4(hh[0], hh[1], hh[2], hh[3]);
            o2 = __builtin_amdgcn_mfma_f32_16x16x32_bf16(a2u.b, b2u.b, o2, 0, 0, 0);
        }

        // store: D rows 0..7 = outputs; lane (q<2, c15): edge c15, o = 4q+j
        if (lane < 32) {
            const float4 r = make_float4(o2.x + b2v.x, o2.y + b2v.y,
                                         o2.z + b2v.z, o2.w + b2v.w);
            *(float4*)(out + obase + (size_t)c15*NET + 4*q) = r;
        }
    }
}

extern "C" void kernel_launch(void* const* d_in, const int* in_sizes, int n_in,
                              void* d_out, int out_size, void* d_ws, size_t ws_size,
                              hipStream_t stream)
{
    const float* h_mol    = (const float*)d_in[0];
    const float* pos_mol  = (const float*)d_in[1];
    const float* h_frag   = (const float*)d_in[2];
    const float* pos_frag = (const float*)d_in[3];
    // d_in[4], d_in[5]: batch indices — contiguous per-graph layout, unused
    const float* W1   = (const float*)d_in[6];
    const float* b1   = (const float*)d_in[7];
    const float* ln_g = (const float*)d_in[8];
    const float* ln_b = (const float*)d_in[9];
    const float* W2   = (const float*)d_in[10];
    const float* b2   = (const float*)d_in[11];

    float* P    = (float*)d_ws;       // 28672 * 256 f32 = 29.36 MB
    float* outp = (float*)d_out;

    hipFuncSetAttribute((const void*)proj_kernel,
                        hipFuncAttributeMaxDynamicSharedMemorySize, PROJ_LDS_BYTES);
    proj_kernel<<<384, 256, PROJ_LDS_BYTES, stream>>>(h_mol, h_frag, W1, b1, P);

    edge_kernel<<<1024, 256, EDGE_LDS_BYTES, stream>>>(
        pos_mol, pos_frag, W1, ln_g, ln_b, W2, b2, P, outp);
}